// Round 9
// baseline (265.518 us; speedup 1.0000x reference)
//
#include <hip/hip_runtime.h>
#include <cstddef>
#include <cstdint>

#define EMB 1024
#define SEQ 1500
#define NB 4
#define NH 16
#define DH 64
#define MTOT (NB*SEQ)   // 6000
#define VTS 1536        // padded V^T row stride (elements)

typedef __bf16 bf16;
typedef __bf16 bf16x4 __attribute__((ext_vector_type(4)));
typedef __bf16 bf16x8 __attribute__((ext_vector_type(8)));
typedef short  s16x4  __attribute__((ext_vector_type(4)));
typedef float  f32x4  __attribute__((ext_vector_type(4)));

#define LOG2E 1.44269504088896340736f

__device__ __forceinline__ void async16(const void* g, const void* l) {
    __builtin_amdgcn_global_load_lds(
        (const __attribute__((address_space(1))) uint32_t*)g,
        (__attribute__((address_space(3))) uint32_t*)l, 16, 0, 0);
}

// pack two fp32 to bf16x2 by truncation: one v_perm_b32
__device__ __forceinline__ uint32_t pack_bf16_trunc(float e0, float e1) {
    return __builtin_amdgcn_perm(__builtin_bit_cast(uint32_t, e1),
                                 __builtin_bit_cast(uint32_t, e0), 0x07060302u);
}

// ---------------------------------------------------------------------------
// fp32 -> bf16 conversion, flat grid over x + 4 weight matrices
// ---------------------------------------------------------------------------
struct CvtArgs {
    const float* xs; bf16* xd;
    const float* w[4]; bf16* wd[4];
};

__global__ __launch_bounds__(256) void cvt_kernel(CvtArgs a) {
    const size_t NX = (size_t)MTOT * EMB;        // 6,144,000 (mult of 4)
    const size_t NW = (size_t)EMB * EMB;         // 1<<20
    const size_t tot = NX + 4 * NW;
    for (size_t i = ((size_t)blockIdx.x * 256 + threadIdx.x) * 4; i < tot;
         i += (size_t)gridDim.x * 1024) {
        const float* s; bf16* d; size_t off;
        if (i < NX) { s = a.xs; d = a.xd; off = i; }
        else {
            size_t j = i - NX;
            int wi = (int)(j >> 20);
            off = j & (NW - 1);
            s = a.w[wi]; d = a.wd[wi];
        }
        float4 v = *(const float4*)(s + off);
        bf16x4 o = { (bf16)v.x, (bf16)v.y, (bf16)v.z, (bf16)v.w };
        *(bf16x4*)(d + off) = o;
    }
}

// ---------------------------------------------------------------------------
// QKV GEMM, 2-WAVE blocks, wave-tile 128x64 (block tile 128x128, BK=32).
// 12 ds_read_b128 feed 32 MFMA per wave-iter (42.7 FLOP/LDS-byte, vs 32 for
// the 4-wave 64x64 variant) and barriers sync only 2 waves. dbuf + XOR
// swizzle + XCD-pinned m-tiles + async16 staging as before.
// proj0 Q / proj1 K: A=W (128 n-rows, frag dim), B=X (m-rows, wave-split).
// proj2 V: A=X (128 m-rows, frag dim), B=W2 (d-rows, wave-split) -> V^T.
// ---------------------------------------------------------------------------
__global__ __launch_bounds__(128) void gemm_fused(
    const bf16* __restrict__ X,
    const bf16* __restrict__ W0, const bf16* __restrict__ W1, const bf16* __restrict__ W2,
    const float* __restrict__ b_q, const float* __restrict__ b_v,
    bf16* __restrict__ Oq, bf16* __restrict__ Ok, bf16* __restrict__ Ovt,
    int M)
{
    __shared__ bf16 As[2][128 * 32];
    __shared__ bf16 Bs[2][128 * 32];
    const int tid = threadIdx.x;
    const int lane = tid & 63, w = tid >> 6;     // w in {0,1}
    const int q = lane >> 4, lr = lane & 15;

    const int id = blockIdx.x;
    const int t_ = id >> 3;
    const int mtile = (id & 7) + (t_ % 6) * 8;   // 0..47
    const int y = t_ / 6;
    const int m0 = mtile * 128;
    const int proj = y >> 3;
    const int n0 = (y & 7) * 128;

    const bf16 *PA, *PB;
    int baseA, baseB, limA, limB;
    if (proj == 2) {               // V: A=X (m-rows), B=W2 (d-rows)
        PA = X;  baseA = m0; limA = M;
        PB = W2; baseB = n0; limB = EMB;
    } else {                       // Q/K: A=W (n-rows), B=X (m-rows)
        PA = (proj == 0) ? W0 : W1;
        baseA = n0; limA = EMB;
        PB = X; baseB = m0; limB = M;
    }

    f32x4 acc[8][4] = {};

    // staging: each wave issues 4 asyncs per tile (16 rows each)
    const int swz_ch = ((lane & 3) ^ ((lane >> 3) & 3)) * 8;
    const bf16* pA[4]; const bf16* pB[4];
#pragma unroll
    for (int j = 0; j < 4; j++) {
        int ra = baseA + (w * 4 + j) * 16 + (lane >> 2); ra = ra < limA ? ra : limA - 1;
        int rb = baseB + (w * 4 + j) * 16 + (lane >> 2); rb = rb < limB ? rb : limB - 1;
        pA[j] = PA + (size_t)ra * EMB + swz_ch;
        pB[j] = PB + (size_t)rb * EMB + swz_ch;
    }

#pragma unroll
    for (int j = 0; j < 4; j++) {
        async16(pA[j], As[0] + (w * 4 + j) * 512);
        async16(pB[j], Bs[0] + (w * 4 + j) * 512);
    }

    const int qsw = (q ^ ((lr >> 1) & 3)) * 8;

    for (int k0 = 0; k0 < EMB; k0 += 32) {
        const int cur = (k0 >> 5) & 1;
        __syncthreads();
        const int nxt = k0 + 32;
        if (nxt < EMB) {
#pragma unroll
            for (int j = 0; j < 4; j++) {
                async16(pA[j] + nxt, As[cur ^ 1] + (w * 4 + j) * 512);
                async16(pB[j] + nxt, Bs[cur ^ 1] + (w * 4 + j) * 512);
            }
        }
        const bf16* Ab = As[cur];
        const bf16* Bb = Bs[cur];
        bf16x8 af[8], bfr[4];
#pragma unroll
        for (int t = 0; t < 8; t++)
            af[t] = *(const bf16x8*)(Ab + (t * 16 + lr) * 32 + qsw);
#pragma unroll
        for (int t = 0; t < 4; t++)
            bfr[t] = *(const bf16x8*)(Bb + (w * 64 + t * 16 + lr) * 32 + qsw);
#pragma unroll
        for (int ti = 0; ti < 8; ti++)
#pragma unroll
            for (int tj = 0; tj < 4; tj++)
                acc[ti][tj] = __builtin_amdgcn_mfma_f32_16x16x32_bf16(
                    af[ti], bfr[tj], acc[ti][tj], 0, 0, 0);
    }

    if (proj <= 1) {
        // D: row(q*4+r) = n (A/W dim, ti<8), col(lr) = m (B/X dim, tj<4)
        const float scale = (proj == 0) ? 0.125f * LOG2E : 1.0f;
        const float* bias = (proj == 0) ? b_q : nullptr;
        bf16* O = (proj == 0) ? Oq : Ok;
#pragma unroll
        for (int tj = 0; tj < 4; tj++) {
            const int m = m0 + w * 64 + tj * 16 + lr;
            if (m >= M) continue;
            const int b_ = m / SEQ, s_ = m % SEQ;
#pragma unroll
            for (int ti = 0; ti < 8; ti++) {
                const int nb = n0 + ti * 16 + q * 4;
                const int h = nb >> 6, d = nb & 63;
                float4 b4 = bias ? *(const float4*)(bias + nb)
                                 : make_float4(0.f, 0.f, 0.f, 0.f);
                bf16x4 o;
                o[0] = (bf16)((acc[ti][tj][0] + b4.x) * scale);
                o[1] = (bf16)((acc[ti][tj][1] + b4.y) * scale);
                o[2] = (bf16)((acc[ti][tj][2] + b4.z) * scale);
                o[3] = (bf16)((acc[ti][tj][3] + b4.w) * scale);
                *(bf16x4*)(O + (((size_t)b_ * NH + h) * SEQ + s_) * DH + d) = o;
            }
        }
    } else {
        // D: row(q*4+r) = s (A/X dim, ti<8, 4 consec), col(lr) = d (B/W dim)
#pragma unroll
        for (int ti = 0; ti < 8; ti++) {
            const int mb = m0 + ti * 16 + q * 4;
            if (mb >= M) continue;
            const int b_ = mb / SEQ, s_ = mb % SEQ;
#pragma unroll
            for (int tj = 0; tj < 4; tj++) {
                const int nb = n0 + w * 64 + tj * 16 + lr;
                const int h = nb >> 6, d = nb & 63;
                const float bv = b_v[nb];
                bf16x4 o;
                o[0] = (bf16)(acc[ti][tj][0] + bv);
                o[1] = (bf16)(acc[ti][tj][1] + bv);
                o[2] = (bf16)(acc[ti][tj][2] + bv);
                o[3] = (bf16)(acc[ti][tj][3] + bv);
                *(bf16x4*)(Ovt + ((size_t)(b_ * NH + h) * DH + d) * VTS + s_) = o;
            }
        }
    }
}

// ---------------------------------------------------------------------------
// Out-projection GEMM: 2-wave blocks, block tile 128m x 64n, wave-tile 64x64
// (waves split on m). A=Wo (64 n-rows), B=ctx (128 m-rows). fp32 b128 stores.
// dbuf + XOR swizzle + XCD-pinned m-tiles. Grid 768 x 128 thr.
// ---------------------------------------------------------------------------
__global__ __launch_bounds__(128) void gemm_out(
    const bf16* __restrict__ X, const bf16* __restrict__ Wo,
    const float* __restrict__ b_o, float* __restrict__ Of, int M)
{
    __shared__ bf16 As[2][64 * 32];    // Wo n-rows
    __shared__ bf16 Bs[2][128 * 32];   // X m-rows
    const int tid = threadIdx.x;
    const int lane = tid & 63, w = tid >> 6;
    const int q = lane >> 4, lr = lane & 15;

    const int id = blockIdx.x;           // 768 = 8 xcd * 96
    const int xcd = id & 7;
    const int h = id >> 3;               // 0..95
    const int mtile = (h % 6) * 8 + xcd; // 0..47 (47 is fully OOB, guarded)
    const int ntile = h / 6;             // 0..15
    const int m0 = mtile * 128, n0 = ntile * 64;

    const int swz_ch = ((lane & 3) ^ ((lane >> 3) & 3)) * 8;
    const bf16* pA[2]; const bf16* pB[4];
#pragma unroll
    for (int j = 0; j < 2; j++) {
        int ra = n0 + (w * 2 + j) * 16 + (lane >> 2);
        pA[j] = Wo + (size_t)ra * EMB + swz_ch;
    }
#pragma unroll
    for (int j = 0; j < 4; j++) {
        int rb = m0 + (w * 4 + j) * 16 + (lane >> 2); rb = rb < M ? rb : M - 1;
        pB[j] = X + (size_t)rb * EMB + swz_ch;
    }

#pragma unroll
    for (int j = 0; j < 2; j++) async16(pA[j], As[0] + (w * 2 + j) * 512);
#pragma unroll
    for (int j = 0; j < 4; j++) async16(pB[j], Bs[0] + (w * 4 + j) * 512);

    f32x4 acc[4][4] = {};
    const int qsw = (q ^ ((lr >> 1) & 3)) * 8;

    for (int k0 = 0; k0 < EMB; k0 += 32) {
        const int cur = (k0 >> 5) & 1;
        __syncthreads();
        const int nxt = k0 + 32;
        if (nxt < EMB) {
#pragma unroll
            for (int j = 0; j < 2; j++)
                async16(pA[j] + nxt, As[cur ^ 1] + (w * 2 + j) * 512);
#pragma unroll
            for (int j = 0; j < 4; j++)
                async16(pB[j] + nxt, Bs[cur ^ 1] + (w * 4 + j) * 512);
        }
        bf16x8 af[4], bfr[4];
#pragma unroll
        for (int t = 0; t < 4; t++)
            af[t] = *(const bf16x8*)(As[cur] + (t * 16 + lr) * 32 + qsw);
#pragma unroll
        for (int t = 0; t < 4; t++)
            bfr[t] = *(const bf16x8*)(Bs[cur] + (w * 64 + t * 16 + lr) * 32 + qsw);
#pragma unroll
        for (int ti = 0; ti < 4; ti++)
#pragma unroll
            for (int tj = 0; tj < 4; tj++)
                acc[ti][tj] = __builtin_amdgcn_mfma_f32_16x16x32_bf16(
                    af[ti], bfr[tj], acc[ti][tj], 0, 0, 0);
    }

    // D: row(q*4+r) = n (Wo dim, ti<4), col(lr) = m (X dim, tj<4)
#pragma unroll
    for (int tj = 0; tj < 4; tj++) {
        const int m = m0 + w * 64 + tj * 16 + lr;
        if (m >= M) continue;
#pragma unroll
        for (int ti = 0; ti < 4; ti++) {
            const int nb = n0 + ti * 16 + q * 4;
            const float4 b4 = *(const float4*)(b_o + nb);
            float4 o;
            o.x = acc[ti][tj][0] + b4.x;
            o.y = acc[ti][tj][1] + b4.y;
            o.z = acc[ti][tj][2] + b4.z;
            o.w = acc[ti][tj][3] + b4.w;
            *(float4*)(Of + (size_t)m * EMB + nb) = o;
        }
    }
}

// ---------------------------------------------------------------------------
// bf16 MFMA flash attention (round-5/8, byte-identical). 128 Q-rows/block,
// S^T = K.Q^T trick, V pre-transposed, global_load_lds dbuf staging with
// XOR swizzle, one barrier/iter, P packed by v_perm truncation, lsum on the
// MFMA pipe, raw exp2.
// ---------------------------------------------------------------------------
__global__ __launch_bounds__(256) void attn_mfma(
    const bf16* __restrict__ Qb, const bf16* __restrict__ Kb,
    const bf16* __restrict__ Vt, bf16* __restrict__ ctx)
{
    __shared__ bf16 Ks[2][64 * 64];
    __shared__ bf16 Vs[2][64 * 64];   // V^T tile: row d, col key
    const int tid = threadIdx.x;
    const int lane = tid & 63, w = tid >> 6;
    const int q = lane >> 4, lr = lane & 15;
    const int bh = blockIdx.x, b_ = bh >> 4, h_ = bh & 15;
    const int q0 = blockIdx.y * 128;
    const size_t base = (size_t)bh * SEQ * DH;
    const size_t vbase = (size_t)bh * DH * VTS;

    int qrow[2];
    bf16x8 qf[2][2];
#pragma unroll
    for (int g = 0; g < 2; g++) {
        qrow[g] = q0 + g * 64 + w * 16 + lr;
        const int qrc = qrow[g] < SEQ ? qrow[g] : (SEQ - 1);
        qf[g][0] = *(const bf16x8*)(Qb + base + (size_t)qrc * DH + q * 8);
        qf[g][1] = *(const bf16x8*)(Qb + base + (size_t)qrc * DH + 32 + q * 8);
    }

    f32x4 oacc[2][4] = {};
    f32x4 lacc[2] = {};
    const s16x4 ones = { (short)0x3F80, (short)0x3F80, (short)0x3F80, (short)0x3F80 };

    const int srow = tid >> 3;                       // 0..31 staging row
    const int sch8 = ((tid & 7) ^ (srow & 7)) * 8;   // swizzled source chunk (elems)
    const int kswz = lr & 7;                          // frag un-swizzle key

    const int NT = (SEQ + 63) / 64;    // 24

    {
        int r0 = srow, r1 = srow + 32;
        async16(Kb + base + (size_t)r0 * DH + sch8, Ks[0] + tid * 8);
        async16(Kb + base + (size_t)r1 * DH + sch8, Ks[0] + tid * 8 + 2048);
        async16(Vt + vbase + (size_t)srow * VTS + sch8,        Vs[0] + tid * 8);
        async16(Vt + vbase + (size_t)(srow + 32) * VTS + sch8, Vs[0] + tid * 8 + 2048);
    }

    for (int kt = 0; kt < NT; kt++) {
        const int k0 = kt * 64;
        const int cur = kt & 1;
        __syncthreads();   // buf[cur] landed (vmcnt drained); buf[cur^1] consumed

        if (kt + 1 < NT) {
            const int kn = k0 + 64;
            int r0 = kn + srow;      if (r0 >= SEQ) r0 = SEQ - 1;
            int r1 = kn + srow + 32; if (r1 >= SEQ) r1 = SEQ - 1;
            async16(Kb + base + (size_t)r0 * DH + sch8, Ks[cur ^ 1] + tid * 8);
            async16(Kb + base + (size_t)r1 * DH + sch8, Ks[cur ^ 1] + tid * 8 + 2048);
            async16(Vt + vbase + (size_t)srow * VTS + kn + sch8,
                    Vs[cur ^ 1] + tid * 8);
            async16(Vt + vbase + (size_t)(srow + 32) * VTS + kn + sch8,
                    Vs[cur ^ 1] + tid * 8 + 2048);
        }

        const bf16* Kc = Ks[cur];
        const bf16* Vc = Vs[cur];

        bf16x8 kf[2][4];
#pragma unroll
        for (int s = 0; s < 2; s++)
#pragma unroll
            for (int mt = 0; mt < 4; mt++)
                kf[s][mt] = *(const bf16x8*)(Kc + (mt * 16 + lr) * 64 +
                                             ((4 * s + q) ^ kswz) * 8);

        s16x4 pf[2][4];
#pragma unroll
        for (int g = 0; g < 2; g++) {
            f32x4 st[4] = {};
#pragma unroll
            for (int s = 0; s < 2; s++)
#pragma unroll
                for (int mt = 0; mt < 4; mt++)
                    st[mt] = __builtin_amdgcn_mfma_f32_16x16x32_bf16(
                        kf[s][mt], qf[g][s], st[mt], 0, 0, 0);

            if (k0 + 64 > SEQ) {
#pragma unroll
                for (int mt = 0; mt < 4; mt++)
#pragma unroll
                    for (int r = 0; r < 4; r++)
                        if (k0 + mt * 16 + q * 4 + r >= SEQ) st[mt][r] = -16384.0f;
            }

#pragma unroll
            for (int mt = 0; mt < 4; mt++) {
                float e0 = __builtin_amdgcn_exp2f(st[mt][0]);
                float e1 = __builtin_amdgcn_exp2f(st[mt][1]);
                float e2 = __builtin_amdgcn_exp2f(st[mt][2]);
                float e3 = __builtin_amdgcn_exp2f(st[mt][3]);
                uint32_t lo = pack_bf16_trunc(e0, e1);
                uint32_t hi = pack_bf16_trunc(e2, e3);
                uint2 pk = { lo, hi };
                pf[g][mt] = __builtin_bit_cast(s16x4, pk);
            }
#pragma unroll
            for (int c = 0; c < 4; c++)
                lacc[g] = __builtin_amdgcn_mfma_f32_16x16x16bf16_1k(
                    ones, pf[g][c], lacc[g], 0, 0, 0);
        }

#pragma unroll
        for (int c = 0; c < 4; c++) {
#pragma unroll
            for (int dt = 0; dt < 4; dt++) {
                const s16x4 vf = __builtin_bit_cast(s16x4,
                    *(const bf16x4*)(Vc + (dt * 16 + lr) * 64 +
                                     ((2 * c + (q >> 1)) ^ kswz) * 8 + (q & 1) * 4));
                oacc[0][dt] = __builtin_amdgcn_mfma_f32_16x16x16bf16_1k(
                    vf, pf[0][c], oacc[0][dt], 0, 0, 0);
                oacc[1][dt] = __builtin_amdgcn_mfma_f32_16x16x16bf16_1k(
                    vf, pf[1][c], oacc[1][dt], 0, 0, 0);
            }
        }
    }

#pragma unroll
    for (int g = 0; g < 2; g++) {
        const float inv = 1.0f / lacc[g][0];
        if (qrow[g] < SEQ) {
            const size_t rowoff = ((size_t)b_ * SEQ + qrow[g]) * EMB + h_ * DH;
#pragma unroll
            for (int dt = 0; dt < 4; dt++) {
                bf16x4 o;
#pragma unroll
                for (int r = 0; r < 4; r++) o[r] = (bf16)(oacc[g][dt][r] * inv);
                *(bf16x4*)(ctx + rowoff + dt * 16 + q * 4) = o;
            }
        }
    }
}

extern "C" void kernel_launch(void* const* d_in, const int* in_sizes, int n_in,
                              void* d_out, int out_size, void* d_ws, size_t ws_size,
                              hipStream_t stream) {
    const float* x     = (const float*)d_in[0];
    const float* q_w   = (const float*)d_in[1];
    const float* q_b   = (const float*)d_in[2];
    const float* k_w   = (const float*)d_in[3];
    const float* v_w   = (const float*)d_in[4];
    const float* v_b   = (const float*)d_in[5];
    const float* out_w = (const float*)d_in[6];
    const float* out_b = (const float*)d_in[7];
    float* out = (float*)d_out;

    const size_t nbuf = (size_t)MTOT * EMB;         // 6,144,000
    const size_t nvt  = (size_t)NB * NH * DH * VTS; // 6,291,456
    const size_t nw   = (size_t)EMB * EMB;          // 1,048,576
    bf16* xb  = (bf16*)d_ws;        // reused as ctx after QKV
    bf16* qws = xb  + nbuf;
    bf16* kws = qws + nbuf;
    bf16* vtw = kws + nbuf;
    bf16* wqb = vtw + nvt;
    bf16* wkb = wqb + nw;
    bf16* wvb = wkb + nw;
    bf16* wob = wvb + nw;
    bf16* ctx = xb;                 // alias: x dead after QKV GEMM

    CvtArgs ca;
    ca.xs = x;      ca.xd = xb;
    ca.w[0] = q_w;  ca.wd[0] = wqb;
    ca.w[1] = k_w;  ca.wd[1] = wkb;
    ca.w[2] = v_w;  ca.wd[2] = wvb;
    ca.w[3] = out_w; ca.wd[3] = wob;
    cvt_kernel<<<dim3(2560), 256, 0, stream>>>(ca);

    // fused QKV projections: 48 m-tiles x 24 (proj,n) slices, XCD-pinned,
    // 2-wave blocks (128 threads)
    gemm_fused<<<dim3(48 * 24), 128, 0, stream>>>(
        xb, wqb, wkb, wvb, q_b, v_b, qws, kws, vtw, MTOT);

    // attention -> ctx [B,S,E] bf16
    attn_mfma<<<dim3(NB * NH, (SEQ + 127) / 128), 256, 0, stream>>>(qws, kws, vtw, ctx);

    // output projection -> d_out (fp32): 128x64 tiles, 768 blocks, 2 waves
    gemm_out<<<dim3(768), 128, 0, stream>>>(ctx, wob, out_b, out, MTOT);
}

// Round 10
// 239.956 us; speedup vs baseline: 1.1065x; 1.1065x over previous
//
#include <hip/hip_runtime.h>
#include <cstddef>
#include <cstdint>

#define EMB 1024
#define SEQ 1500
#define NB 4
#define NH 16
#define DH 64
#define MTOT (NB*SEQ)   // 6000
#define VTS 1536        // padded V^T row stride (elements)

typedef __bf16 bf16;
typedef __bf16 bf16x4 __attribute__((ext_vector_type(4)));
typedef __bf16 bf16x8 __attribute__((ext_vector_type(8)));
typedef short  s16x4  __attribute__((ext_vector_type(4)));
typedef float  f32x4  __attribute__((ext_vector_type(4)));

#define LOG2E 1.44269504088896340736f

__device__ __forceinline__ void async16(const void* g, const void* l) {
    __builtin_amdgcn_global_load_lds(
        (const __attribute__((address_space(1))) uint32_t*)g,
        (__attribute__((address_space(3))) uint32_t*)l, 16, 0, 0);
}

// pack two fp32 to bf16x2 by truncation: one v_perm_b32
__device__ __forceinline__ uint32_t pack_bf16_trunc(float e0, float e1) {
    return __builtin_amdgcn_perm(__builtin_bit_cast(uint32_t, e1),
                                 __builtin_bit_cast(uint32_t, e0), 0x07060302u);
}

// ---------------------------------------------------------------------------
// fp32 -> bf16 conversion, flat grid over x + 4 weight matrices
// ---------------------------------------------------------------------------
struct CvtArgs {
    const float* xs; bf16* xd;
    const float* w[4]; bf16* wd[4];
};

__global__ __launch_bounds__(256) void cvt_kernel(CvtArgs a) {
    const size_t NX = (size_t)MTOT * EMB;        // 6,144,000 (mult of 4)
    const size_t NW = (size_t)EMB * EMB;         // 1<<20
    const size_t tot = NX + 4 * NW;
    for (size_t i = ((size_t)blockIdx.x * 256 + threadIdx.x) * 4; i < tot;
         i += (size_t)gridDim.x * 1024) {
        const float* s; bf16* d; size_t off;
        if (i < NX) { s = a.xs; d = a.xd; off = i; }
        else {
            size_t j = i - NX;
            int wi = (int)(j >> 20);
            off = j & (NW - 1);
            s = a.w[wi]; d = a.wd[wi];
        }
        float4 v = *(const float4*)(s + off);
        bf16x4 o = { (bf16)v.x, (bf16)v.y, (bf16)v.z, (bf16)v.w };
        *(bf16x4*)(d + off) = o;
    }
}

// ---------------------------------------------------------------------------
// QKV GEMM (r8 known-good: 71 us): 128x128 tile, BK=32, 4-wave blocks,
// dbuf, XOR swizzle, XCD-pinned m-tiles. proj0 Q (swapped, 0.125*log2e),
// proj1 K (swapped), proj2 V (normal -> V^T store).
// ---------------------------------------------------------------------------
__global__ __launch_bounds__(256) void gemm_fused(
    const bf16* __restrict__ X,
    const bf16* __restrict__ W0, const bf16* __restrict__ W1, const bf16* __restrict__ W2,
    const float* __restrict__ b_q, const float* __restrict__ b_v,
    bf16* __restrict__ Oq, bf16* __restrict__ Ok, bf16* __restrict__ Ovt,
    int M)
{
    __shared__ bf16 As[2][128 * 32];
    __shared__ bf16 Bs[2][128 * 32];
    const int tid = threadIdx.x;
    const int lane = tid & 63, w = tid >> 6;
    const int q = lane >> 4, lr = lane & 15;
    const int wr = w >> 1, wc = w & 1;

    const int id = blockIdx.x;
    const int t_ = id >> 3;
    const int mtile = (id & 7) + (t_ % 6) * 8;     // 0..47
    const int y = t_ / 6;
    const int m0 = mtile * 128;
    const int proj = y >> 3;
    const int n0 = (y & 7) * 128;

    const bf16 *PA, *PB;
    int baseA, baseB, limA, limB;
    if (proj == 2) {
        PA = X;  baseA = m0; limA = M;
        PB = W2; baseB = n0; limB = EMB;
    } else {
        PA = (proj == 0) ? W0 : W1;
        baseA = n0; limA = EMB;
        PB = X; baseB = m0; limB = M;
    }

    f32x4 acc[4][4] = {};

    const int srow = w * 32 + (lane >> 2);
    const int swz_ch = (((lane & 3) ^ ((lane >> 3) & 3))) * 8;
    const bf16* pA[2]; const bf16* pB[2];
#pragma unroll
    for (int i = 0; i < 2; i++) {
        int ra = baseA + srow + i * 16; ra = ra < limA ? ra : limA - 1;
        int rb = baseB + srow + i * 16; rb = rb < limB ? rb : limB - 1;
        pA[i] = PA + (size_t)ra * EMB + swz_ch;
        pB[i] = PB + (size_t)rb * EMB + swz_ch;
    }

#pragma unroll
    for (int i = 0; i < 2; i++) {
        async16(pA[i], As[0] + (w * 2 + i) * 512);
        async16(pB[i], Bs[0] + (w * 2 + i) * 512);
    }

    const int qsw = (q ^ ((lr >> 1) & 3)) * 8;
    const int arow = (wr * 64 + lr) * 32;
    const int brow = (wc * 64 + lr) * 32;

    for (int k0 = 0; k0 < EMB; k0 += 32) {
        const int cur = (k0 >> 5) & 1;
        __syncthreads();
        const int nxt = k0 + 32;
        if (nxt < EMB) {
#pragma unroll
            for (int i = 0; i < 2; i++) {
                async16(pA[i] + nxt, As[cur ^ 1] + (w * 2 + i) * 512);
                async16(pB[i] + nxt, Bs[cur ^ 1] + (w * 2 + i) * 512);
            }
        }
        const bf16* Ab = As[cur];
        const bf16* Bb = Bs[cur];
        bf16x8 af[4], bfr[4];
#pragma unroll
        for (int t = 0; t < 4; t++) {
            af[t]  = *(const bf16x8*)(Ab + arow + t * 512 + qsw);
            bfr[t] = *(const bf16x8*)(Bb + brow + t * 512 + qsw);
        }
#pragma unroll
        for (int ti = 0; ti < 4; ti++)
#pragma unroll
            for (int tj = 0; tj < 4; tj++)
                acc[ti][tj] = __builtin_amdgcn_mfma_f32_16x16x32_bf16(
                    af[ti], bfr[tj], acc[ti][tj], 0, 0, 0);
    }

    if (proj <= 1) {
        const float scale = (proj == 0) ? 0.125f * LOG2E : 1.0f;
        const float* bias = (proj == 0) ? b_q : nullptr;
        bf16* O = (proj == 0) ? Oq : Ok;
#pragma unroll
        for (int tj = 0; tj < 4; tj++) {
            const int m = m0 + wc * 64 + tj * 16 + lr;
            if (m >= M) continue;
            const int b_ = m / SEQ, s_ = m % SEQ;
#pragma unroll
            for (int ti = 0; ti < 4; ti++) {
                const int nb = n0 + wr * 64 + ti * 16 + q * 4;
                const int h = nb >> 6, d = nb & 63;
                float4 b4 = bias ? *(const float4*)(bias + nb)
                                 : make_float4(0.f, 0.f, 0.f, 0.f);
                bf16x4 o;
                o[0] = (bf16)((acc[ti][tj][0] + b4.x) * scale);
                o[1] = (bf16)((acc[ti][tj][1] + b4.y) * scale);
                o[2] = (bf16)((acc[ti][tj][2] + b4.z) * scale);
                o[3] = (bf16)((acc[ti][tj][3] + b4.w) * scale);
                *(bf16x4*)(O + (((size_t)b_ * NH + h) * SEQ + s_) * DH + d) = o;
            }
        }
    } else {
#pragma unroll
        for (int ti = 0; ti < 4; ti++) {
            const int mb = m0 + wr * 64 + ti * 16 + q * 4;
            if (mb >= M) continue;
            const int b_ = mb / SEQ, s_ = mb % SEQ;
#pragma unroll
            for (int tj = 0; tj < 4; tj++) {
                const int nb = n0 + wc * 64 + tj * 16 + lr;
                const int h = nb >> 6, d = nb & 63;
                const float bv = b_v[nb];
                bf16x4 o;
                o[0] = (bf16)(acc[ti][tj][0] + bv);
                o[1] = (bf16)(acc[ti][tj][1] + bv);
                o[2] = (bf16)(acc[ti][tj][2] + bv);
                o[3] = (bf16)(acc[ti][tj][3] + bv);
                *(bf16x4*)(Ovt + ((size_t)(b_ * NH + h) * DH + d) * VTS + s_) = o;
            }
        }
    }
}

// ---------------------------------------------------------------------------
// Out-projection GEMM (r8): 128m x 64n tile, 4-wave blocks, grid 768.
// A=Wo (64 n-rows), B=ctx (128 m-rows), D=C^T -> fp32 b128 stores.
// dbuf + XOR swizzle + XCD-pinned m-tiles.
// ---------------------------------------------------------------------------
__global__ __launch_bounds__(256) void gemm_out(
    const bf16* __restrict__ X, const bf16* __restrict__ Wo,
    const float* __restrict__ b_o, float* __restrict__ Of, int M)
{
    __shared__ bf16 As[2][64 * 32];    // Wo n-rows
    __shared__ bf16 Bs[2][128 * 32];   // X m-rows
    const int tid = threadIdx.x;
    const int lane = tid & 63, w = tid >> 6;
    const int q = lane >> 4, lr = lane & 15;
    const int wc = w & 1, wr = w >> 1;   // wc: m-half (64), wr: n-half (32)

    const int id = blockIdx.x;           // 768 = 8 xcd * 96
    const int xcd = id & 7;
    const int h = id >> 3;               // 0..95
    const int mtile = (h % 6) * 8 + xcd; // 0..47
    const int ntile = h / 6;             // 0..15
    const int m0 = mtile * 128, n0 = ntile * 64;

    const int cs = ((tid & 3) ^ ((tid >> 3) & 3)) * 8;   // swizzled source chunk
    const bf16* pA = Wo + (size_t)(n0 + (tid >> 2)) * EMB + cs;
    const int srow = w * 32 + (lane >> 2);
    const bf16* pB[2];
#pragma unroll
    for (int i = 0; i < 2; i++) {
        int rb = m0 + srow + i * 16; rb = rb < M ? rb : M - 1;
        pB[i] = X + (size_t)rb * EMB + cs;
    }

    async16(pA, As[0] + w * 512);
#pragma unroll
    for (int i = 0; i < 2; i++)
        async16(pB[i], Bs[0] + (w * 2 + i) * 512);

    f32x4 acc[2][4] = {};
    const int qsw = (q ^ ((lr >> 1) & 3)) * 8;
    const int arow = (wr * 32 + lr) * 32;
    const int brow = (wc * 64 + lr) * 32;

    for (int k0 = 0; k0 < EMB; k0 += 32) {
        const int cur = (k0 >> 5) & 1;
        __syncthreads();
        const int nxt = k0 + 32;
        if (nxt < EMB) {
            async16(pA + nxt, As[cur ^ 1] + w * 512);
#pragma unroll
            for (int i = 0; i < 2; i++)
                async16(pB[i] + nxt, Bs[cur ^ 1] + (w * 2 + i) * 512);
        }
        bf16x8 af[2], bfr[4];
#pragma unroll
        for (int t = 0; t < 2; t++)
            af[t] = *(const bf16x8*)(As[cur] + arow + t * 512 + qsw);
#pragma unroll
        for (int t = 0; t < 4; t++)
            bfr[t] = *(const bf16x8*)(Bs[cur] + brow + t * 512 + qsw);
#pragma unroll
        for (int ti = 0; ti < 2; ti++)
#pragma unroll
            for (int tj = 0; tj < 4; tj++)
                acc[ti][tj] = __builtin_amdgcn_mfma_f32_16x16x32_bf16(
                    af[ti], bfr[tj], acc[ti][tj], 0, 0, 0);
    }

    // D = C^T: n = n0 + wr*32 + ti*16 + q*4 + r, m = m0 + wc*64 + tj*16 + lr
#pragma unroll
    for (int tj = 0; tj < 4; tj++) {
        const int m = m0 + wc * 64 + tj * 16 + lr;
        if (m >= M) continue;
#pragma unroll
        for (int ti = 0; ti < 2; ti++) {
            const int nb = n0 + wr * 32 + ti * 16 + q * 4;
            const float4 b4 = *(const float4*)(b_o + nb);
            float4 o;
            o.x = acc[ti][tj][0] + b4.x;
            o.y = acc[ti][tj][1] + b4.y;
            o.z = acc[ti][tj][2] + b4.z;
            o.w = acc[ti][tj][3] + b4.w;
            *(float4*)(Of + (size_t)m * EMB + nb) = o;
        }
    }
}

// ---------------------------------------------------------------------------
// bf16 MFMA flash attention, now 192 Q-rows/block (THREE 16-row groups per
// wave). K-frags and V-frags are loaded once per iter and shared across all
// 3 groups -> 33% less total LDS traffic vs 2-group at same MFMA FLOPs
// (attn's CU-level bottleneck). Everything else as r8: S^T = K.Q^T trick,
// V pre-transposed, async16 dbuf staging with XOR swizzle, 1 barrier/iter,
// P packed by v_perm truncation, lsum on the MFMA pipe, raw exp2.
// ---------------------------------------------------------------------------
#define QG 3
__global__ __launch_bounds__(256) void attn_mfma(
    const bf16* __restrict__ Qb, const bf16* __restrict__ Kb,
    const bf16* __restrict__ Vt, bf16* __restrict__ ctx)
{
    __shared__ bf16 Ks[2][64 * 64];
    __shared__ bf16 Vs[2][64 * 64];   // V^T tile: row d, col key
    const int tid = threadIdx.x;
    const int lane = tid & 63, w = tid >> 6;
    const int q = lane >> 4, lr = lane & 15;
    const int bh = blockIdx.x, b_ = bh >> 4, h_ = bh & 15;
    const int q0 = blockIdx.y * (QG * 64);
    const size_t base = (size_t)bh * SEQ * DH;
    const size_t vbase = (size_t)bh * DH * VTS;

    int qrow[QG];
    bf16x8 qf[QG][2];
#pragma unroll
    for (int g = 0; g < QG; g++) {
        qrow[g] = q0 + g * 64 + w * 16 + lr;
        const int qrc = qrow[g] < SEQ ? qrow[g] : (SEQ - 1);
        qf[g][0] = *(const bf16x8*)(Qb + base + (size_t)qrc * DH + q * 8);
        qf[g][1] = *(const bf16x8*)(Qb + base + (size_t)qrc * DH + 32 + q * 8);
    }

    f32x4 oacc[QG][4] = {};
    f32x4 lacc[QG] = {};
    const s16x4 ones = { (short)0x3F80, (short)0x3F80, (short)0x3F80, (short)0x3F80 };

    const int srow = tid >> 3;                       // 0..31 staging row
    const int sch8 = ((tid & 7) ^ (srow & 7)) * 8;   // swizzled source chunk (elems)
    const int kswz = lr & 7;                          // frag un-swizzle key

    const int NT = (SEQ + 63) / 64;    // 24

    {
        int r0 = srow, r1 = srow + 32;
        async16(Kb + base + (size_t)r0 * DH + sch8, Ks[0] + tid * 8);
        async16(Kb + base + (size_t)r1 * DH + sch8, Ks[0] + tid * 8 + 2048);
        async16(Vt + vbase + (size_t)srow * VTS + sch8,        Vs[0] + tid * 8);
        async16(Vt + vbase + (size_t)(srow + 32) * VTS + sch8, Vs[0] + tid * 8 + 2048);
    }

    for (int kt = 0; kt < NT; kt++) {
        const int k0 = kt * 64;
        const int cur = kt & 1;
        __syncthreads();   // buf[cur] landed (vmcnt drained); buf[cur^1] consumed

        if (kt + 1 < NT) {
            const int kn = k0 + 64;
            int r0 = kn + srow;      if (r0 >= SEQ) r0 = SEQ - 1;
            int r1 = kn + srow + 32; if (r1 >= SEQ) r1 = SEQ - 1;
            async16(Kb + base + (size_t)r0 * DH + sch8, Ks[cur ^ 1] + tid * 8);
            async16(Kb + base + (size_t)r1 * DH + sch8, Ks[cur ^ 1] + tid * 8 + 2048);
            async16(Vt + vbase + (size_t)srow * VTS + kn + sch8,
                    Vs[cur ^ 1] + tid * 8);
            async16(Vt + vbase + (size_t)(srow + 32) * VTS + kn + sch8,
                    Vs[cur ^ 1] + tid * 8 + 2048);
        }

        const bf16* Kc = Ks[cur];
        const bf16* Vc = Vs[cur];

        // K fragments, shared by all Q-groups
        bf16x8 kf[2][4];
#pragma unroll
        for (int s = 0; s < 2; s++)
#pragma unroll
            for (int mt = 0; mt < 4; mt++)
                kf[s][mt] = *(const bf16x8*)(Kc + (mt * 16 + lr) * 64 +
                                             ((4 * s + q) ^ kswz) * 8);

        s16x4 pf[QG][4];
#pragma unroll
        for (int g = 0; g < QG; g++) {
            f32x4 st[4] = {};
#pragma unroll
            for (int s = 0; s < 2; s++)
#pragma unroll
                for (int mt = 0; mt < 4; mt++)
                    st[mt] = __builtin_amdgcn_mfma_f32_16x16x32_bf16(
                        kf[s][mt], qf[g][s], st[mt], 0, 0, 0);

            if (k0 + 64 > SEQ) {
#pragma unroll
                for (int mt = 0; mt < 4; mt++)
#pragma unroll
                    for (int r = 0; r < 4; r++)
                        if (k0 + mt * 16 + q * 4 + r >= SEQ) st[mt][r] = -16384.0f;
            }

#pragma unroll
            for (int mt = 0; mt < 4; mt++) {
                float e0 = __builtin_amdgcn_exp2f(st[mt][0]);
                float e1 = __builtin_amdgcn_exp2f(st[mt][1]);
                float e2 = __builtin_amdgcn_exp2f(st[mt][2]);
                float e3 = __builtin_amdgcn_exp2f(st[mt][3]);
                uint32_t lo = pack_bf16_trunc(e0, e1);
                uint32_t hi = pack_bf16_trunc(e2, e3);
                uint2 pk = { lo, hi };
                pf[g][mt] = __builtin_bit_cast(s16x4, pk);
            }
#pragma unroll
            for (int c = 0; c < 4; c++)
                lacc[g] = __builtin_amdgcn_mfma_f32_16x16x16bf16_1k(
                    ones, pf[g][c], lacc[g], 0, 0, 0);
        }

        // O^T += V^T . P^T, V fragments shared by all groups
#pragma unroll
        for (int c = 0; c < 4; c++) {
#pragma unroll
            for (int dt = 0; dt < 4; dt++) {
                const s16x4 vf = __builtin_bit_cast(s16x4,
                    *(const bf16x4*)(Vc + (dt * 16 + lr) * 64 +
                                     ((2 * c + (q >> 1)) ^ kswz) * 8 + (q & 1) * 4));
#pragma unroll
                for (int g = 0; g < QG; g++)
                    oacc[g][dt] = __builtin_amdgcn_mfma_f32_16x16x16bf16_1k(
                        vf, pf[g][c], oacc[g][dt], 0, 0, 0);
            }
        }
    }

    // epilogue: lane lr's col of lacc == its Q-row sum; no shuffles needed
#pragma unroll
    for (int g = 0; g < QG; g++) {
        const float inv = 1.0f / lacc[g][0];
        if (qrow[g] < SEQ) {
            const size_t rowoff = ((size_t)b_ * SEQ + qrow[g]) * EMB + h_ * DH;
#pragma unroll
            for (int dt = 0; dt < 4; dt++) {
                bf16x4 o;
#pragma unroll
                for (int r = 0; r < 4; r++) o[r] = (bf16)(oacc[g][dt][r] * inv);
                *(bf16x4*)(ctx + rowoff + dt * 16 + q * 4) = o;
            }
        }
    }
}

extern "C" void kernel_launch(void* const* d_in, const int* in_sizes, int n_in,
                              void* d_out, int out_size, void* d_ws, size_t ws_size,
                              hipStream_t stream) {
    const float* x     = (const float*)d_in[0];
    const float* q_w   = (const float*)d_in[1];
    const float* q_b   = (const float*)d_in[2];
    const float* k_w   = (const float*)d_in[3];
    const float* v_w   = (const float*)d_in[4];
    const float* v_b   = (const float*)d_in[5];
    const float* out_w = (const float*)d_in[6];
    const float* out_b = (const float*)d_in[7];
    float* out = (float*)d_out;

    const size_t nbuf = (size_t)MTOT * EMB;         // 6,144,000
    const size_t nvt  = (size_t)NB * NH * DH * VTS; // 6,291,456
    const size_t nw   = (size_t)EMB * EMB;          // 1,048,576
    bf16* xb  = (bf16*)d_ws;        // reused as ctx after QKV
    bf16* qws = xb  + nbuf;
    bf16* kws = qws + nbuf;
    bf16* vtw = kws + nbuf;
    bf16* wqb = vtw + nvt;
    bf16* wkb = wqb + nw;
    bf16* wvb = wkb + nw;
    bf16* wob = wvb + nw;
    bf16* ctx = xb;                 // alias: x dead after QKV GEMM

    CvtArgs ca;
    ca.xs = x;      ca.xd = xb;
    ca.w[0] = q_w;  ca.wd[0] = wqb;
    ca.w[1] = k_w;  ca.wd[1] = wkb;
    ca.w[2] = v_w;  ca.wd[2] = wvb;
    ca.w[3] = out_w; ca.wd[3] = wob;
    cvt_kernel<<<dim3(2560), 256, 0, stream>>>(ca);

    // fused QKV projections: 48 m-tiles x 24 (proj,n) slices, XCD-pinned
    gemm_fused<<<dim3(48 * 24), 256, 0, stream>>>(
        xb, wqb, wkb, wvb, q_b, v_b, qws, kws, vtw, MTOT);

    // attention -> ctx [B,S,E] bf16; 192 Q-rows per block
    attn_mfma<<<dim3(NB * NH, (SEQ + QG * 64 - 1) / (QG * 64)), 256, 0, stream>>>(
        qws, kws, vtw, ctx);

    // output projection -> d_out (fp32): 128x64 tiles, 768 blocks (3/CU)
    gemm_out<<<dim3(768), 256, 0, stream>>>(ctx, wob, out_b, out, MTOT);
}